// Round 2
// baseline (631.742 us; speedup 1.0000x reference)
//
#include <hip/hip_runtime.h>

#define N_ 32
#define C_ 128
#define H_ 32
#define W_ 32
#define T_ 12
#define R_ 64
#define HW_ (H_*W_)           // 1024
#define HWT_ (HW_*T_)         // 12288
#define CHWT_ ((size_t)C_*HW_*T_)  // 1572864

__device__ __forceinline__ float sigm(float v) {
    return 1.0f / (1.0f + __expf(-v));
}

// K1a: ts_in[n,t,h,w] = mean_c x[n,c,h,w,t]
// block = (hw_chunk of 64, n); each thread owns 3 (hw,t) positions, sums over c in registers.
__global__ __launch_bounds__(256) void k_tsin(const float* __restrict__ x,
                                              float* __restrict__ ts_in) {
    int chunk = blockIdx.x;      // 0..15
    int n = blockIdx.y;
    int tid = threadIdx.x;
    int hw0 = chunk * 64;
    const float* xp = x + (size_t)n * CHWT_ + (size_t)hw0 * T_;
    float s0 = 0.f, s1 = 0.f, s2 = 0.f;
    #pragma unroll 4
    for (int c = 0; c < C_; ++c) {
        const float* p = xp + (size_t)c * HWT_;
        s0 += p[tid];
        s1 += p[tid + 256];
        s2 += p[tid + 512];
    }
    float sums[3] = {s0, s1, s2};
    #pragma unroll
    for (int j = 0; j < 3; ++j) {
        int p = tid + 256 * j;
        int hwl = p / T_;
        int t = p - hwl * T_;
        ts_in[(n * T_ + t) * HW_ + hw0 + hwl] = sums[j] * (1.0f / 128.0f);
    }
}

// K1b: pooled[n,t,c] = mean_{hw} x[n,c,hw,t]
// block per (c, n); stride-256 coalesced reads; 256 mod 12 = 4 => each thread's t cycles over 3 residues.
__global__ __launch_bounds__(256) void k_pool(const float* __restrict__ x,
                                              float* __restrict__ pooled) {
    int c = blockIdx.x;
    int n = blockIdx.y;
    int tid = threadIdx.x;
    const float* xp = x + (size_t)(n * C_ + c) * HWT_;
    float a0 = 0.f, a1 = 0.f, a2 = 0.f;
    #pragma unroll 4
    for (int k = 0; k < 48; k += 3) {
        a0 += xp[tid + 256 * k];
        a1 += xp[tid + 256 * (k + 1)];
        a2 += xp[tid + 256 * (k + 2)];
    }
    __shared__ float psum[T_];
    if (tid < T_) psum[tid] = 0.f;
    __syncthreads();
    int tb = tid % T_;
    atomicAdd(&psum[tb], a0);
    atomicAdd(&psum[(tb + 4) % T_], a1);
    atomicAdd(&psum[(tb + 8) % T_], a2);
    __syncthreads();
    if (tid < T_) pooled[(n * T_ + tid) * C_ + c] = psum[tid] * (1.0f / 1024.0f);
}

// K2: TS[n,r,s] = sigmoid(conv3x3(ts_in)[n,r,h,w] + ts_b[r])
// block per (h, n); rows h-1..h+1 (zero-padded to width 34) + all weights in LDS.
__global__ __launch_bounds__(256) void k_conv(const float* __restrict__ ts_in,
                                              const float* __restrict__ ts_w,
                                              const float* __restrict__ ts_b,
                                              float* __restrict__ TS) {
    int h = blockIdx.x;
    int n = blockIdx.y;
    int tid = threadIdx.x;
    __shared__ float rows[3 * T_ * 34];   // 1224 floats
    __shared__ float wl[R_ * 108];        // 6912 floats
    for (int i = tid; i < 3 * T_ * 34; i += 256) {
        int kh = i / (T_ * 34);
        int rem = i - kh * (T_ * 34);
        int t = rem / 34;
        int wp = rem - t * 34;
        int hr = h + kh - 1;
        float v = 0.f;
        if (wp >= 1 && wp <= 32 && hr >= 0 && hr < H_)
            v = ts_in[((n * T_ + t) * H_ + hr) * W_ + (wp - 1)];
        rows[i] = v;
    }
    for (int i = tid; i < R_ * 108; i += 256) wl[i] = ts_w[i];
    __syncthreads();
    int r = tid >> 2;
    int j = tid & 3;
    float acc[8];
    float b = ts_b[r];
    #pragma unroll
    for (int wi = 0; wi < 8; ++wi) acc[wi] = b;
    for (int t = 0; t < T_; ++t) {
        #pragma unroll
        for (int kh = 0; kh < 3; ++kh) {
            #pragma unroll
            for (int kw = 0; kw < 3; ++kw) {
                float wt = wl[r * 108 + t * 9 + kh * 3 + kw];
                const float* rp = &rows[(kh * T_ + t) * 34 + kw];
                #pragma unroll
                for (int wi = 0; wi < 8; ++wi) {
                    acc[wi] += rp[j + 4 * wi] * wt;
                }
            }
        }
    }
    float* outp = TS + (size_t)(n * R_ + r) * HW_ + h * W_;
    #pragma unroll
    for (int wi = 0; wi < 8; ++wi) {
        outp[j + 4 * wi] = sigm(acc[wi]);
    }
}

// K3: TC[n,t,r] and SC[n,c,r]; block per n. tc_w transposed in LDS to avoid bank conflicts.
__global__ __launch_bounds__(256) void k_lin(const float* __restrict__ pooled,
                                             const float* __restrict__ tc_w,
                                             const float* __restrict__ tc_b,
                                             const float* __restrict__ sc_w,
                                             const float* __restrict__ sc_b,
                                             float* __restrict__ TC,
                                             float* __restrict__ SC) {
    int n = blockIdx.x;
    int tid = threadIdx.x;
    __shared__ float pl[T_ * C_];    // 1536
    __shared__ float twt[C_ * R_];   // 8192, [c][r]
    __shared__ float sw[R_ * T_];    // 768
    for (int i = tid; i < T_ * C_; i += 256) pl[i] = pooled[n * T_ * C_ + i];
    for (int i = tid; i < C_ * R_; i += 256) {
        int r = i >> 7;
        int c = i & 127;
        twt[c * R_ + r] = tc_w[i];
    }
    for (int i = tid; i < R_ * T_; i += 256) sw[i] = sc_w[i];
    __syncthreads();
    for (int o = tid; o < T_ * R_; o += 256) {
        int t = o >> 6;
        int r = o & 63;
        float acc = tc_b[r];
        #pragma unroll 4
        for (int c = 0; c < C_; ++c) acc += pl[t * C_ + c] * twt[c * R_ + r];
        TC[n * T_ * R_ + o] = sigm(acc);
    }
    for (int o = tid; o < C_ * R_; o += 256) {
        int c = o >> 6;
        int r = o & 63;
        float acc = sc_b[r];
        #pragma unroll
        for (int t = 0; t < T_; ++t) acc += pl[t * C_ + c] * sw[r * T_ + t];
        SC[n * C_ * R_ + o] = sigm(acc);
    }
}

// K4: out[n,c,h,w,t] = relu( (Σ_r TS[n,r,s]·TC[n,t,r]·SC[n,c,r]) * x[n,c,h,w,t] )
// block = (s_chunk of 16, n), 192 threads; thread = one (s,t) column, loops all 128 c.
// w[r] = TC[t,r]*TS[r,s] in 64 VGPRs; SC[n] in LDS read as wave-uniform float4 broadcast.
__global__ __launch_bounds__(192) void k_main(const float* __restrict__ x,
                                              const float* __restrict__ TS,
                                              const float* __restrict__ TC,
                                              const float* __restrict__ SC,
                                              float* __restrict__ out) {
    int schunk = blockIdx.x;   // 0..63
    int n = blockIdx.y;
    int tid = threadIdx.x;
    __shared__ __align__(16) float scl[C_ * R_];  // 8192 floats = 32 KB
    __shared__ float tst[R_ * 16];                // 1024
    __shared__ float tcl[T_ * R_];                // 768
    int s0 = schunk * 16;
    for (int i = tid; i < C_ * R_; i += 192) scl[i] = SC[(size_t)n * C_ * R_ + i];
    for (int i = tid; i < R_ * 16; i += 192) {
        int r = i >> 4;
        int sl = i & 15;
        tst[i] = TS[(size_t)(n * R_ + r) * HW_ + s0 + sl];
    }
    for (int i = tid; i < T_ * R_; i += 192) tcl[i] = TC[n * T_ * R_ + i];
    __syncthreads();
    int sl = tid / T_;
    int t = tid - sl * T_;
    float w[R_];
    #pragma unroll
    for (int r = 0; r < R_; ++r) w[r] = tcl[t * R_ + r] * tst[r * 16 + sl];
    size_t base = (size_t)n * CHWT_ + (size_t)s0 * T_ + tid;
    #pragma unroll 2
    for (int c = 0; c < C_; ++c) {
        const float4* sv = (const float4*)(scl + c * R_);
        float acc = 0.f;
        #pragma unroll
        for (int r4 = 0; r4 < R_ / 4; ++r4) {
            float4 v = sv[r4];
            acc += v.x * w[4 * r4] + v.y * w[4 * r4 + 1] +
                   v.z * w[4 * r4 + 2] + v.w * w[4 * r4 + 3];
        }
        size_t idx = base + (size_t)c * HWT_;
        float g = x[idx];
        float rr = acc * g;
        out[idx] = rr > 0.f ? rr : 0.f;
    }
}

extern "C" void kernel_launch(void* const* d_in, const int* in_sizes, int n_in,
                              void* d_out, int out_size, void* d_ws, size_t ws_size,
                              hipStream_t stream) {
    const float* x    = (const float*)d_in[0];
    const float* ts_w = (const float*)d_in[1];
    const float* ts_b = (const float*)d_in[2];
    const float* tc_w = (const float*)d_in[3];
    const float* tc_b = (const float*)d_in[4];
    const float* sc_w = (const float*)d_in[5];
    const float* sc_b = (const float*)d_in[6];
    float* out = (float*)d_out;

    float* ws     = (float*)d_ws;
    float* ts_in  = ws;                       // 393216 floats
    float* pooled = ts_in + 393216;           // 49152
    float* TS     = pooled + 49152;           // 2097152
    float* TC     = TS + 2097152;             // 24576
    float* SC     = TC + 24576;               // 262144  (total ~10.8 MB)

    hipLaunchKernelGGL(k_tsin, dim3(16, 32), dim3(256), 0, stream, x, ts_in);
    hipLaunchKernelGGL(k_pool, dim3(128, 32), dim3(256), 0, stream, x, pooled);
    hipLaunchKernelGGL(k_conv, dim3(32, 32), dim3(256), 0, stream, ts_in, ts_w, ts_b, TS);
    hipLaunchKernelGGL(k_lin, dim3(32), dim3(256), 0, stream,
                       pooled, tc_w, tc_b, sc_w, sc_b, TC, SC);
    hipLaunchKernelGGL(k_main, dim3(64, 32), dim3(192), 0, stream, x, TS, TC, SC, out);
}